// Round 5
// baseline (376.847 us; speedup 1.0000x reference)
//
#include <hip/hip_runtime.h>
#include <hip/hip_bf16.h>

#define S_LEN 2048
#define BATCH 2
#define DMODEL 1024
#define NHEAD 16
#define DHEAD 64
#define WINDOW 256
#define MROWS (S_LEN * BATCH)   // 4096

typedef unsigned short u16;
typedef __attribute__((ext_vector_type(8))) short bf16x8;
typedef __attribute__((ext_vector_type(4))) float f32x4;

__device__ __forceinline__ float b2f(u16 u) {
    union { unsigned int i; float f; } x; x.i = ((unsigned int)u) << 16; return x.f;
}
__device__ __forceinline__ u16 f2b(float f) {
    union { float f; unsigned int i; } x; x.f = f;
    unsigned int r = x.i + 0x7fffu + ((x.i >> 16) & 1u);
    return (u16)(r >> 16);
}
__device__ __forceinline__ bf16x8 ld8f(const float* __restrict__ p) {
    bf16x8 r;
    #pragma unroll
    for (int i = 0; i < 8; i++) r[i] = (short)f2b(p[i]);
    return r;
}

// Fused QKV projection. Block = 64 rows x 128 cols (4 waves, 2x2 of 32x64).
// grid (MROWS/64, 24): blockIdx.y>>3 selects Q/K/V.
// Q: (acc+bias)*1/(8*exp(beta_h)) -> qbuf[row][col] bf16
// K: acc+bias -> kbuf[row][col] bf16
// V: acc+bias -> Vt[b][h][dh][s] bf16 (transposed)
__global__ __launch_bounds__(256) void gemm_qkv(
    const float* __restrict__ x,
    const float* __restrict__ Wq, const float* __restrict__ bq,
    const float* __restrict__ Wk, const float* __restrict__ bk,
    const float* __restrict__ Wv, const float* __restrict__ bv,
    const float* __restrict__ beta,
    u16* __restrict__ qbuf, u16* __restrict__ kbuf, u16* __restrict__ vt)
{
    const int lane = threadIdx.x & 63;
    const int wave = threadIdx.x >> 6;
    const int r15 = lane & 15, g = lane >> 4;
    const int m0 = blockIdx.x * 64 + (wave >> 1) * 32;
    const int range = blockIdx.y >> 3;                       // 0=Q 1=K 2=V
    const int n0 = (blockIdx.y & 7) * 128 + (wave & 1) * 64; // 0..1023 local
    const float* W    = (range == 0) ? Wq : (range == 1) ? Wk : Wv;
    const float* bias = (range == 0) ? bq : (range == 1) ? bk : bv;
    const float* a0 = x + (size_t)(m0 + r15) * DMODEL + g * 8;
    const float* w0 = W + (size_t)(n0 + r15) * DMODEL + g * 8;
    f32x4 acc[2][4] = {};
    for (int k = 0; k < DMODEL; k += 32) {
        bf16x8 af[2], bf[4];
        #pragma unroll
        for (int mi = 0; mi < 2; mi++) af[mi] = ld8f(a0 + (size_t)mi * 16 * DMODEL + k);
        #pragma unroll
        for (int ni = 0; ni < 4; ni++) bf[ni] = ld8f(w0 + (size_t)ni * 16 * DMODEL + k);
        #pragma unroll
        for (int mi = 0; mi < 2; mi++)
            #pragma unroll
            for (int ni = 0; ni < 4; ni++)
                acc[mi][ni] = __builtin_amdgcn_mfma_f32_16x16x32_bf16(
                    af[mi], bf[ni], acc[mi][ni], 0, 0, 0);
    }
    #pragma unroll
    for (int ni = 0; ni < 4; ni++) {
        const int col = n0 + ni * 16 + r15;
        const float bv_ = bias[col];
        float scale = 1.0f;
        if (range == 0) scale = 1.0f / (8.0f * __expf(beta[col >> 6]));
        #pragma unroll
        for (int mi = 0; mi < 2; mi++)
            #pragma unroll
            for (int r = 0; r < 4; r++) {
                const int row = m0 + mi * 16 + g * 4 + r;
                const float val = acc[mi][ni][r] + bv_;
                if (range == 0) {
                    qbuf[(size_t)row * DMODEL + col] = f2b(val * scale);
                } else if (range == 1) {
                    kbuf[(size_t)row * DMODEL + col] = f2b(val);
                } else {
                    // row = s*BATCH+b ; col = h*64+dh
                    const int b = row & 1, s = row >> 1;
                    vt[((size_t)(b * NHEAD + (col >> 6)) * DHEAD + (col & 63)) * S_LEN + s]
                        = f2b(val);
                }
            }
    }
}

// Sliding-window attention, Q pre-projected/pre-scaled, V transposed.
// One wave per (b,h,16-query tile). All MFMAs 16x16x32_bf16.
__global__ __launch_bounds__(256) void attn2(
    const u16* __restrict__ qb, const u16* __restrict__ kb,
    const u16* __restrict__ vt, u16* __restrict__ O)
{
    const int lane = threadIdx.x & 63;
    const int wave = threadIdx.x >> 6;
    const int wid = blockIdx.x * 4 + wave;                   // 0..4095
    const int qt = wid & (S_LEN / 16 - 1);
    const int h  = (wid >> 7) & (NHEAD - 1);
    const int b  = wid >> 11;
    const int qstart = qt * 16;
    const int r15 = lane & 15, g = lane >> 4;
    const int i_glob = qstart + r15;

    const u16* qrow = qb + ((size_t)i_glob * BATCH + b) * DMODEL + h * DHEAD;
    const bf16x8 qf0 = *reinterpret_cast<const bf16x8*>(qrow + g * 8);
    const bf16x8 qf1 = *reinterpret_cast<const bf16x8*>(qrow + 32 + g * 8);
    const u16* vbase = vt + (size_t)(b * NHEAD + h) * DHEAD * S_LEN;

    float m = -1e30f, lsum = 0.0f;
    f32x4 o[4] = {};
    const int kt0 = (qstart >= WINDOW) ? (qstart - WINDOW) : 0;

    for (int kt = kt0; kt <= qstart; kt += 32) {
        f32x4 st0 = {0.f, 0.f, 0.f, 0.f}, st1 = {0.f, 0.f, 0.f, 0.f};
        {
            const int kr = min(kt + r15, S_LEN - 1);
            const u16* kp = kb + ((size_t)kr * BATCH + b) * DMODEL + h * DHEAD;
            const bf16x8 ka  = *reinterpret_cast<const bf16x8*>(kp + g * 8);
            const bf16x8 kb2 = *reinterpret_cast<const bf16x8*>(kp + 32 + g * 8);
            st0 = __builtin_amdgcn_mfma_f32_16x16x32_bf16(ka,  qf0, st0, 0, 0, 0);
            st0 = __builtin_amdgcn_mfma_f32_16x16x32_bf16(kb2, qf1, st0, 0, 0, 0);
        }
        {
            const int kr = min(kt + 16 + r15, S_LEN - 1);
            const u16* kp = kb + ((size_t)kr * BATCH + b) * DMODEL + h * DHEAD;
            const bf16x8 ka  = *reinterpret_cast<const bf16x8*>(kp + g * 8);
            const bf16x8 kb2 = *reinterpret_cast<const bf16x8*>(kp + 32 + g * 8);
            st1 = __builtin_amdgcn_mfma_f32_16x16x32_bf16(ka,  qf0, st1, 0, 0, 0);
            st1 = __builtin_amdgcn_mfma_f32_16x16x32_bf16(kb2, qf1, st1, 0, 0, 0);
        }

        float p0[4], p1[4];
        #pragma unroll
        for (int r = 0; r < 4; r++) {
            const int j0 = kt + g * 4 + r;
            const int d0 = i_glob - j0;
            p0[r] = (d0 < 0 || d0 >= WINDOW) ? -3e38f : st0[r];
            const int j1 = kt + 16 + g * 4 + r;
            const int d1 = i_glob - j1;
            p1[r] = (d1 < 0 || d1 >= WINDOW) ? -3e38f : st1[r];
        }
        float pmax = -3e38f;
        #pragma unroll
        for (int r = 0; r < 4; r++) pmax = fmaxf(pmax, fmaxf(p0[r], p1[r]));
        pmax = fmaxf(pmax, __shfl_xor(pmax, 16));
        pmax = fmaxf(pmax, __shfl_xor(pmax, 32));
        const float mnew = fmaxf(m, pmax);
        const float alpha = __expf(m - mnew);
        float psum = 0.0f;
        #pragma unroll
        for (int r = 0; r < 4; r++) {
            p0[r] = __expf(p0[r] - mnew);
            p1[r] = __expf(p1[r] - mnew);
            psum += p0[r] + p1[r];
        }
        psum += __shfl_xor(psum, 16);
        psum += __shfl_xor(psum, 32);
        lsum = lsum * alpha + psum;
        m = mnew;
        #pragma unroll
        for (int c = 0; c < 4; c++)
            #pragma unroll
            for (int r = 0; r < 4; r++) o[c][r] *= alpha;

        // assemble P^T B-fragment: reg i <- key kt + 8g + i
        bf16x8 pf;
        const int base = ((g & 1) * 2) * 16 + r15;
        #pragma unroll
        for (int i = 0; i < 8; i++) {
            const int src = base + (i >> 2) * 16;
            const float v0 = __shfl(p0[i & 3], src);
            const float v1 = __shfl(p1[i & 3], src);
            pf[i] = (short)f2b((g < 2) ? v0 : v1);
        }

        // PV: o^T[dh][q] += V^T · P^T, V fragment = single bf16x8 from Vt
        int srow = kt + g * 8;
        if (srow >= S_LEN) srow = 0;                 // fully-masked run, finite garbage ok
        #pragma unroll
        for (int c = 0; c < 4; c++) {
            const bf16x8 vf = *reinterpret_cast<const bf16x8*>(
                vbase + (size_t)(c * 16 + r15) * S_LEN + srow);
            o[c] = __builtin_amdgcn_mfma_f32_16x16x32_bf16(vf, pf, o[c], 0, 0, 0);
        }
    }

    const float inv = 1.0f / lsum;
    #pragma unroll
    for (int c = 0; c < 4; c++)
        #pragma unroll
        for (int r = 0; r < 4; r++) {
            const int dh = c * 16 + g * 4 + r;
            O[((size_t)i_glob * BATCH + b) * DMODEL + h * DHEAD + dh] = f2b(o[c][r] * inv);
        }
}

// Output GEMM: A bf16 [4096][1024], Wo/bo fp32, out fp32. 64x128 blocks.
__global__ __launch_bounds__(256) void gemm_out(
    const u16* __restrict__ A, const float* __restrict__ W,
    const float* __restrict__ bias, float* __restrict__ C)
{
    const int lane = threadIdx.x & 63;
    const int wave = threadIdx.x >> 6;
    const int r15 = lane & 15, g = lane >> 4;
    const int m0 = blockIdx.x * 64 + (wave >> 1) * 32;
    const int n0 = blockIdx.y * 128 + (wave & 1) * 64;
    const u16* a0 = A + (size_t)(m0 + r15) * DMODEL + g * 8;
    const float* w0 = W + (size_t)(n0 + r15) * DMODEL + g * 8;
    f32x4 acc[2][4] = {};
    for (int k = 0; k < DMODEL; k += 32) {
        bf16x8 af[2], bf[4];
        #pragma unroll
        for (int mi = 0; mi < 2; mi++)
            af[mi] = *reinterpret_cast<const bf16x8*>(a0 + (size_t)mi * 16 * DMODEL + k);
        #pragma unroll
        for (int ni = 0; ni < 4; ni++) bf[ni] = ld8f(w0 + (size_t)ni * 16 * DMODEL + k);
        #pragma unroll
        for (int mi = 0; mi < 2; mi++)
            #pragma unroll
            for (int ni = 0; ni < 4; ni++)
                acc[mi][ni] = __builtin_amdgcn_mfma_f32_16x16x32_bf16(
                    af[mi], bf[ni], acc[mi][ni], 0, 0, 0);
    }
    #pragma unroll
    for (int ni = 0; ni < 4; ni++) {
        const int col = n0 + ni * 16 + r15;
        const float bv_ = bias[col];
        #pragma unroll
        for (int mi = 0; mi < 2; mi++)
            #pragma unroll
            for (int r = 0; r < 4; r++) {
                const int row = m0 + mi * 16 + g * 4 + r;
                C[(size_t)row * DMODEL + col] = acc[mi][ni][r] + bv_;
            }
    }
}

extern "C" void kernel_launch(void* const* d_in, const int* in_sizes, int n_in,
                              void* d_out, int out_size, void* d_ws, size_t ws_size,
                              hipStream_t stream) {
    const float* x    = (const float*)d_in[0];
    const float* Wq   = (const float*)d_in[1];
    const float* bq   = (const float*)d_in[2];
    const float* Wk   = (const float*)d_in[3];
    const float* bk   = (const float*)d_in[4];
    const float* Wv   = (const float*)d_in[5];
    const float* bv   = (const float*)d_in[6];
    const float* Wo   = (const float*)d_in[7];
    const float* bo   = (const float*)d_in[8];
    const float* beta = (const float*)d_in[9];
    float* out = (float*)d_out;
    u16* ws = (u16*)d_ws;

    const size_t MAT = (size_t)MROWS * DMODEL;   // 4M elems
    u16* qbuf = (u16*)d_out;        // d_out[0:8MB]   staged, overwritten at end
    u16* kbuf = (u16*)d_out + MAT;  // d_out[8:16MB]  staged, overwritten at end
    u16* vtb  = ws;                 // 8 MB  V transposed [b][h][dh][s]
    u16* abuf = ws + MAT;           // 8 MB  attention output

    dim3 g1(MROWS / 64, 24);        // 1536 blocks
    gemm_qkv<<<g1, 256, 0, stream>>>(x, Wq, bq, Wk, bk, Wv, bv, beta, qbuf, kbuf, vtb);

    attn2<<<BATCH * NHEAD * (S_LEN / 16) / 4, 256, 0, stream>>>(qbuf, kbuf, vtb, abuf);

    dim3 g2(MROWS / 64, 8);         // 512 blocks
    gemm_out<<<g2, 256, 0, stream>>>(abuf, Wo, bo, out);
}

// Round 6
// 193.826 us; speedup vs baseline: 1.9443x; 1.9443x over previous
//
#include <hip/hip_runtime.h>
#include <hip/hip_bf16.h>

#define S_LEN 2048
#define BATCH 2
#define DMODEL 1024
#define NHEAD 16
#define DHEAD 64
#define WINDOW 256
#define MROWS (S_LEN * BATCH)   // 4096

typedef unsigned short u16;
typedef __attribute__((ext_vector_type(8))) short bf16x8;
typedef __attribute__((ext_vector_type(4))) float f32x4;

__device__ __forceinline__ float b2f(u16 u) {
    union { unsigned int i; float f; } x; x.i = ((unsigned int)u) << 16; return x.f;
}
__device__ __forceinline__ u16 f2b(float f) {
    union { float f; unsigned int i; } x; x.f = f;
    unsigned int r = x.i + 0x7fffu + ((x.i >> 16) & 1u);
    return (u16)(r >> 16);
}
__device__ __forceinline__ bf16x8 ld8f(const float* __restrict__ p) {
    bf16x8 r;
    #pragma unroll
    for (int i = 0; i < 8; i++) r[i] = (short)f2b(p[i]);
    return r;
}
// fragment load: bf16 direct (16B) or fp32+convert
template<bool BF>
__device__ __forceinline__ bf16x8 ldrow(const void* __restrict__ base, size_t elemOff) {
    if constexpr (BF) return *reinterpret_cast<const bf16x8*>((const u16*)base + elemOff);
    else              return ld8f((const float*)base + elemOff);
}

// One streaming pass: cast x(4M) | Wq(1M) | Wk(1M) | Wv(1M) | Wo(1M) fp32 -> bf16.
// 4096 blocks x 256 thr x 8 elems = 8M elems exactly.
__global__ __launch_bounds__(256) void cast_all(
    const float* __restrict__ x,  const float* __restrict__ Wq,
    const float* __restrict__ Wk, const float* __restrict__ Wv,
    const float* __restrict__ Wo,
    u16* __restrict__ xb, u16* __restrict__ wb, u16* __restrict__ wob)
{
    const size_t idx = ((size_t)blockIdx.x * 256 + threadIdx.x) * 8;
    const size_t M1 = 1048576;
    const float* src; u16* dst;
    if (idx < 4 * M1)      { src = x  + idx;            dst = xb  + idx; }
    else if (idx < 5 * M1) { src = Wq + (idx - 4 * M1); dst = wb  + (idx - 4 * M1); }
    else if (idx < 6 * M1) { src = Wk + (idx - 5 * M1); dst = wb  + (idx - 4 * M1); }
    else if (idx < 7 * M1) { src = Wv + (idx - 6 * M1); dst = wb  + (idx - 4 * M1); }
    else                   { src = Wo + (idx - 7 * M1); dst = wob + (idx - 7 * M1); }
    *reinterpret_cast<bf16x8*>(dst) = ld8f(src);
}

// Fused QKV GEMM, 128x128 block (4 waves, 64x64/wave, acc 4x4).
// grid (MROWS/128, 24): blockIdx.y>>3 = 0/1/2 -> Q/K/V epilogue.
template<bool ABF, bool WBF>
__global__ __launch_bounds__(256) void gemm_qkv_t(
    const void* __restrict__ A_,
    const void* __restrict__ Wq_, const void* __restrict__ Wk_, const void* __restrict__ Wv_,
    const float* __restrict__ bq, const float* __restrict__ bk, const float* __restrict__ bv,
    const float* __restrict__ beta,
    u16* __restrict__ qbuf, u16* __restrict__ kbuf, u16* __restrict__ vt)
{
    const int lane = threadIdx.x & 63;
    const int wave = threadIdx.x >> 6;
    const int r15 = lane & 15, g = lane >> 4;
    const int m0 = blockIdx.x * 128 + (wave >> 1) * 64;
    const int range = blockIdx.y >> 3;                        // 0=Q 1=K 2=V (block-uniform)
    const int n0 = (blockIdx.y & 7) * 128 + (wave & 1) * 64;  // local col 0..1023
    const void* W_ = (range == 0) ? Wq_ : (range == 1) ? Wk_ : Wv_;
    const float* bias = (range == 0) ? bq : (range == 1) ? bk : bv;
    const size_t aBase = (size_t)(m0 + r15) * DMODEL + g * 8;
    const size_t wBase = (size_t)(n0 + r15) * DMODEL + g * 8;
    f32x4 acc[4][4] = {};
    for (int k = 0; k < DMODEL; k += 32) {
        bf16x8 af[4], bf[4];
        #pragma unroll
        for (int mi = 0; mi < 4; mi++) af[mi] = ldrow<ABF>(A_, aBase + (size_t)mi * 16 * DMODEL + k);
        #pragma unroll
        for (int ni = 0; ni < 4; ni++) bf[ni] = ldrow<WBF>(W_, wBase + (size_t)ni * 16 * DMODEL + k);
        #pragma unroll
        for (int mi = 0; mi < 4; mi++)
            #pragma unroll
            for (int ni = 0; ni < 4; ni++)
                acc[mi][ni] = __builtin_amdgcn_mfma_f32_16x16x32_bf16(
                    af[mi], bf[ni], acc[mi][ni], 0, 0, 0);
    }
    #pragma unroll
    for (int ni = 0; ni < 4; ni++) {
        const int col = n0 + ni * 16 + r15;       // 0..1023
        const float bv_ = bias[col];
        float scale = 1.0f;
        if (range == 0) scale = 1.0f / (8.0f * __expf(beta[col >> 6]));
        #pragma unroll
        for (int mi = 0; mi < 4; mi++)
            #pragma unroll
            for (int r = 0; r < 4; r++) {
                const int row = m0 + mi * 16 + g * 4 + r;
                const float val = acc[mi][ni][r] + bv_;
                if (range == 0) {
                    qbuf[(size_t)row * DMODEL + col] = f2b(val * scale);
                } else if (range == 1) {
                    kbuf[(size_t)row * DMODEL + col] = f2b(val);
                } else {
                    const int b = row & 1, s = row >> 1;
                    vt[((size_t)(b * NHEAD + (col >> 6)) * DHEAD + (col & 63)) * S_LEN + s]
                        = f2b(val);
                }
            }
    }
}

// Sliding-window attention, Q pre-projected/pre-scaled, V transposed. (unchanged)
__global__ __launch_bounds__(256) void attn2(
    const u16* __restrict__ qb, const u16* __restrict__ kb,
    const u16* __restrict__ vt, u16* __restrict__ O)
{
    const int lane = threadIdx.x & 63;
    const int wave = threadIdx.x >> 6;
    const int wid = blockIdx.x * 4 + wave;
    const int qt = wid & (S_LEN / 16 - 1);
    const int h  = (wid >> 7) & (NHEAD - 1);
    const int b  = wid >> 11;
    const int qstart = qt * 16;
    const int r15 = lane & 15, g = lane >> 4;
    const int i_glob = qstart + r15;

    const u16* qrow = qb + ((size_t)i_glob * BATCH + b) * DMODEL + h * DHEAD;
    const bf16x8 qf0 = *reinterpret_cast<const bf16x8*>(qrow + g * 8);
    const bf16x8 qf1 = *reinterpret_cast<const bf16x8*>(qrow + 32 + g * 8);
    const u16* vbase = vt + (size_t)(b * NHEAD + h) * DHEAD * S_LEN;

    float m = -1e30f, lsum = 0.0f;
    f32x4 o[4] = {};
    const int kt0 = (qstart >= WINDOW) ? (qstart - WINDOW) : 0;

    for (int kt = kt0; kt <= qstart; kt += 32) {
        f32x4 st0 = {0.f, 0.f, 0.f, 0.f}, st1 = {0.f, 0.f, 0.f, 0.f};
        {
            const int kr = min(kt + r15, S_LEN - 1);
            const u16* kp = kb + ((size_t)kr * BATCH + b) * DMODEL + h * DHEAD;
            const bf16x8 ka  = *reinterpret_cast<const bf16x8*>(kp + g * 8);
            const bf16x8 kb2 = *reinterpret_cast<const bf16x8*>(kp + 32 + g * 8);
            st0 = __builtin_amdgcn_mfma_f32_16x16x32_bf16(ka,  qf0, st0, 0, 0, 0);
            st0 = __builtin_amdgcn_mfma_f32_16x16x32_bf16(kb2, qf1, st0, 0, 0, 0);
        }
        {
            const int kr = min(kt + 16 + r15, S_LEN - 1);
            const u16* kp = kb + ((size_t)kr * BATCH + b) * DMODEL + h * DHEAD;
            const bf16x8 ka  = *reinterpret_cast<const bf16x8*>(kp + g * 8);
            const bf16x8 kb2 = *reinterpret_cast<const bf16x8*>(kp + 32 + g * 8);
            st1 = __builtin_amdgcn_mfma_f32_16x16x32_bf16(ka,  qf0, st1, 0, 0, 0);
            st1 = __builtin_amdgcn_mfma_f32_16x16x32_bf16(kb2, qf1, st1, 0, 0, 0);
        }

        float p0[4], p1[4];
        #pragma unroll
        for (int r = 0; r < 4; r++) {
            const int j0 = kt + g * 4 + r;
            const int d0 = i_glob - j0;
            p0[r] = (d0 < 0 || d0 >= WINDOW) ? -3e38f : st0[r];
            const int j1 = kt + 16 + g * 4 + r;
            const int d1 = i_glob - j1;
            p1[r] = (d1 < 0 || d1 >= WINDOW) ? -3e38f : st1[r];
        }
        float pmax = -3e38f;
        #pragma unroll
        for (int r = 0; r < 4; r++) pmax = fmaxf(pmax, fmaxf(p0[r], p1[r]));
        pmax = fmaxf(pmax, __shfl_xor(pmax, 16));
        pmax = fmaxf(pmax, __shfl_xor(pmax, 32));
        const float mnew = fmaxf(m, pmax);
        const float alpha = __expf(m - mnew);
        float psum = 0.0f;
        #pragma unroll
        for (int r = 0; r < 4; r++) {
            p0[r] = __expf(p0[r] - mnew);
            p1[r] = __expf(p1[r] - mnew);
            psum += p0[r] + p1[r];
        }
        psum += __shfl_xor(psum, 16);
        psum += __shfl_xor(psum, 32);
        lsum = lsum * alpha + psum;
        m = mnew;
        #pragma unroll
        for (int c = 0; c < 4; c++)
            #pragma unroll
            for (int r = 0; r < 4; r++) o[c][r] *= alpha;

        bf16x8 pf;
        const int base = ((g & 1) * 2) * 16 + r15;
        #pragma unroll
        for (int i = 0; i < 8; i++) {
            const int src = base + (i >> 2) * 16;
            const float v0 = __shfl(p0[i & 3], src);
            const float v1 = __shfl(p1[i & 3], src);
            pf[i] = (short)f2b((g < 2) ? v0 : v1);
        }

        int srow = kt + g * 8;
        if (srow >= S_LEN) srow = 0;
        #pragma unroll
        for (int c = 0; c < 4; c++) {
            const bf16x8 vf = *reinterpret_cast<const bf16x8*>(
                vbase + (size_t)(c * 16 + r15) * S_LEN + srow);
            o[c] = __builtin_amdgcn_mfma_f32_16x16x32_bf16(vf, pf, o[c], 0, 0, 0);
        }
    }

    const float inv = 1.0f / lsum;
    #pragma unroll
    for (int c = 0; c < 4; c++)
        #pragma unroll
        for (int r = 0; r < 4; r++) {
            const int dh = c * 16 + g * 4 + r;
            O[((size_t)i_glob * BATCH + b) * DMODEL + h * DHEAD + dh] = f2b(o[c][r] * inv);
        }
}

// Output GEMM: A bf16 [4096][1024], W (bf16 or fp32) [1024][1024], out fp32.
// 64x128 block (512 blocks, acc 2x4).
template<bool WBF>
__global__ __launch_bounds__(256) void gemm_out_t(
    const u16* __restrict__ A, const void* __restrict__ W_,
    const float* __restrict__ bias, float* __restrict__ C)
{
    const int lane = threadIdx.x & 63;
    const int wave = threadIdx.x >> 6;
    const int r15 = lane & 15, g = lane >> 4;
    const int m0 = blockIdx.x * 64 + (wave >> 1) * 32;
    const int n0 = blockIdx.y * 128 + (wave & 1) * 64;
    const u16* a0 = A + (size_t)(m0 + r15) * DMODEL + g * 8;
    const size_t wBase = (size_t)(n0 + r15) * DMODEL + g * 8;
    f32x4 acc[2][4] = {};
    for (int k = 0; k < DMODEL; k += 32) {
        bf16x8 af[2], bf[4];
        #pragma unroll
        for (int mi = 0; mi < 2; mi++)
            af[mi] = *reinterpret_cast<const bf16x8*>(a0 + (size_t)mi * 16 * DMODEL + k);
        #pragma unroll
        for (int ni = 0; ni < 4; ni++) bf[ni] = ldrow<WBF>(W_, wBase + (size_t)ni * 16 * DMODEL + k);
        #pragma unroll
        for (int mi = 0; mi < 2; mi++)
            #pragma unroll
            for (int ni = 0; ni < 4; ni++)
                acc[mi][ni] = __builtin_amdgcn_mfma_f32_16x16x32_bf16(
                    af[mi], bf[ni], acc[mi][ni], 0, 0, 0);
    }
    #pragma unroll
    for (int ni = 0; ni < 4; ni++) {
        const int col = n0 + ni * 16 + r15;
        const float bv_ = bias[col];
        #pragma unroll
        for (int mi = 0; mi < 2; mi++)
            #pragma unroll
            for (int r = 0; r < 4; r++) {
                const int row = m0 + mi * 16 + g * 4 + r;
                C[(size_t)row * DMODEL + col] = acc[mi][ni][r] + bv_;
            }
    }
}

extern "C" void kernel_launch(void* const* d_in, const int* in_sizes, int n_in,
                              void* d_out, int out_size, void* d_ws, size_t ws_size,
                              hipStream_t stream) {
    const float* x    = (const float*)d_in[0];
    const float* Wq   = (const float*)d_in[1];
    const float* bq   = (const float*)d_in[2];
    const float* Wk   = (const float*)d_in[3];
    const float* bk   = (const float*)d_in[4];
    const float* Wv   = (const float*)d_in[5];
    const float* bv   = (const float*)d_in[6];
    const float* Wo   = (const float*)d_in[7];
    const float* bo   = (const float*)d_in[8];
    const float* beta = (const float*)d_in[9];
    float* out = (float*)d_out;
    u16* ws = (u16*)d_ws;

    const size_t M4 = (size_t)MROWS * DMODEL;   // 4M elems
    u16* qbuf = (u16*)d_out;        // d_out[0:8MB]  (overwritten by final GEMM)
    u16* kbuf = (u16*)d_out + M4;   // d_out[8:16MB]
    u16* vtb  = ws;                 // 8 MB  V^T [b][h][dh][s]
    u16* abuf = ws + M4;            // 8 MB  attention out

    const int nattn = BATCH * NHEAD * (S_LEN / 16) / 4;  // 1024 blocks
    dim3 gqkv(MROWS / 128, 24);     // 768 blocks
    dim3 gout(MROWS / 64, 8);       // 512 blocks

    if (ws_size >= (size_t)32 * 1024 * 1024) {
        u16* xb  = ws + 2 * M4;             // 8 MB
        u16* wb  = ws + 3 * M4;             // 6 MB  [Wq;Wk;Wv] bf16
        u16* wob = ws + 3 * M4 + 3145728;   // 2 MB
        cast_all<<<4096, 256, 0, stream>>>(x, Wq, Wk, Wv, Wo, xb, wb, wob);
        gemm_qkv_t<true, true><<<gqkv, 256, 0, stream>>>(
            xb, wb, wb + 1048576, wb + 2097152, bq, bk, bv, beta, qbuf, kbuf, vtb);
        attn2<<<nattn, 256, 0, stream>>>(qbuf, kbuf, vtb, abuf);
        gemm_out_t<true><<<gout, 256, 0, stream>>>(abuf, wob, bo, out);
    } else {
        gemm_qkv_t<false, false><<<gqkv, 256, 0, stream>>>(
            x, Wq, Wk, Wv, bq, bk, bv, beta, qbuf, kbuf, vtb);
        attn2<<<nattn, 256, 0, stream>>>(qbuf, kbuf, vtb, abuf);
        gemm_out_t<false><<<gout, 256, 0, stream>>>(abuf, Wo, bo, out);
    }
}

// Round 7
// 111.847 us; speedup vs baseline: 3.3693x; 1.7330x over previous
//
#include <hip/hip_runtime.h>
#include <hip/hip_bf16.h>

#define S_LEN 2048
#define BATCH 2
#define DMODEL 1024
#define NHEAD 16
#define DHEAD 64
#define WINDOW 256
#define MROWS (S_LEN * BATCH)   // 4096

typedef unsigned short u16;
typedef __attribute__((ext_vector_type(8))) short bf16x8;
typedef __attribute__((ext_vector_type(4))) float f32x4;

typedef const __attribute__((address_space(1))) void gvoid;
typedef __attribute__((address_space(3))) void lvoid;

__device__ __forceinline__ float b2f(u16 u) {
    union { unsigned int i; float f; } x; x.i = ((unsigned int)u) << 16; return x.f;
}
__device__ __forceinline__ u16 f2b(float f) {
    union { float f; unsigned int i; } x; x.f = f;
    unsigned int r = x.i + 0x7fffu + ((x.i >> 16) & 1u);
    return (u16)(r >> 16);
}
__device__ __forceinline__ bf16x8 ld8f(const float* __restrict__ p) {
    bf16x8 r;
    #pragma unroll
    for (int i = 0; i < 8; i++) r[i] = (short)f2b(p[i]);
    return r;
}
template<bool BF>
__device__ __forceinline__ bf16x8 ldrow(const void* __restrict__ base, size_t elemOff) {
    if constexpr (BF) return *reinterpret_cast<const bf16x8*>((const u16*)base + elemOff);
    else              return ld8f((const float*)base + elemOff);
}

// One streaming pass: cast x(4M) | Wq | Wk | Wv | Wo fp32 -> bf16 (8M elems).
__global__ __launch_bounds__(256) void cast_all(
    const float* __restrict__ x,  const float* __restrict__ Wq,
    const float* __restrict__ Wk, const float* __restrict__ Wv,
    const float* __restrict__ Wo,
    u16* __restrict__ xb, u16* __restrict__ wb, u16* __restrict__ wob)
{
    const size_t idx = ((size_t)blockIdx.x * 256 + threadIdx.x) * 8;
    const size_t M1 = 1048576;
    const float* src; u16* dst;
    if (idx < 4 * M1)      { src = x  + idx;            dst = xb  + idx; }
    else if (idx < 5 * M1) { src = Wq + (idx - 4 * M1); dst = wb  + (idx - 4 * M1); }
    else if (idx < 6 * M1) { src = Wk + (idx - 5 * M1); dst = wb  + (idx - 4 * M1); }
    else if (idx < 7 * M1) { src = Wv + (idx - 6 * M1); dst = wb  + (idx - 4 * M1); }
    else                   { src = Wo + (idx - 7 * M1); dst = wob + (idx - 7 * M1); }
    *reinterpret_cast<bf16x8*>(dst) = ld8f(src);
}

// ---------------- m97-structure staged GEMM pieces ----------------
// Tile 128x128, BK=32, 4 waves (64x64 each), LDS-staged via global_load_lds(16B).
// LDS tile layout: [128 rows][32 cols] bf16, linear. Stage thread t, round ro:
// row = ro*64 + t/4, col = (t%4)*8.

// Fused QKV: grid (32, 24); blockIdx.y>>3 = 0/1/2 -> Q/K/V epilogue.
__global__ __launch_bounds__(256) void gemm_qkv_s(
    const u16* __restrict__ A, const u16* __restrict__ Wall,
    const float* __restrict__ bq, const float* __restrict__ bk, const float* __restrict__ bv,
    const float* __restrict__ beta,
    u16* __restrict__ qbuf, u16* __restrict__ kbuf, u16* __restrict__ vt)
{
    __shared__ u16 lA[128 * 32];
    __shared__ u16 lB[128 * 32];
    const int tid = threadIdx.x;
    const int lane = tid & 63, wave = tid >> 6;
    const int r15 = lane & 15, g = lane >> 4;
    const int m0 = blockIdx.x * 128;
    const int range = blockIdx.y >> 3;                       // 0=Q 1=K 2=V
    const int n0 = (blockIdx.y & 7) * 128;                   // local col
    const u16* W = Wall + (size_t)range * DMODEL * DMODEL;
    const float* bias = (range == 0) ? bq : (range == 1) ? bk : bv;

    const int srow = tid >> 2, scol = (tid & 3) * 8;
    const u16* aSrc = A + (size_t)(m0 + srow) * DMODEL + scol;
    const u16* wSrc = W + (size_t)(n0 + srow) * DMODEL + scol;
    const int ldsW = wave * 1024;                            // byte offset per wave
    const int mrow = (wave >> 1) * 64, nrow = (wave & 1) * 64;

    f32x4 acc[4][4] = {};
    for (int kk = 0; kk < DMODEL; kk += 32) {
        __syncthreads();
        #pragma unroll
        for (int ro = 0; ro < 2; ro++) {
            __builtin_amdgcn_global_load_lds(
                (gvoid*)(aSrc + (size_t)ro * 64 * DMODEL + kk),
                (lvoid*)((char*)lA + ro * 4096 + ldsW), 16, 0, 0);
            __builtin_amdgcn_global_load_lds(
                (gvoid*)(wSrc + (size_t)ro * 64 * DMODEL + kk),
                (lvoid*)((char*)lB + ro * 4096 + ldsW), 16, 0, 0);
        }
        __syncthreads();
        bf16x8 af[4], bf[4];
        #pragma unroll
        for (int mi = 0; mi < 4; mi++)
            af[mi] = *reinterpret_cast<const bf16x8*>(&lA[(mrow + mi * 16 + r15) * 32 + g * 8]);
        #pragma unroll
        for (int ni = 0; ni < 4; ni++)
            bf[ni] = *reinterpret_cast<const bf16x8*>(&lB[(nrow + ni * 16 + r15) * 32 + g * 8]);
        #pragma unroll
        for (int mi = 0; mi < 4; mi++)
            #pragma unroll
            for (int ni = 0; ni < 4; ni++)
                acc[mi][ni] = __builtin_amdgcn_mfma_f32_16x16x32_bf16(
                    af[mi], bf[ni], acc[mi][ni], 0, 0, 0);
    }
    #pragma unroll
    for (int ni = 0; ni < 4; ni++) {
        const int col = n0 + nrow + ni * 16 + r15;           // 0..1023
        const float bv_ = bias[col];
        float scale = 1.0f;
        if (range == 0) scale = 1.0f / (8.0f * __expf(beta[col >> 6]));
        #pragma unroll
        for (int mi = 0; mi < 4; mi++)
            #pragma unroll
            for (int r = 0; r < 4; r++) {
                const int row = m0 + mrow + mi * 16 + g * 4 + r;
                const float val = acc[mi][ni][r] + bv_;
                if (range == 0) {
                    qbuf[(size_t)row * DMODEL + col] = f2b(val * scale);
                } else if (range == 1) {
                    kbuf[(size_t)row * DMODEL + col] = f2b(val);
                } else {
                    const int b = row & 1, s = row >> 1;
                    vt[((size_t)(b * NHEAD + (col >> 6)) * DHEAD + (col & 63)) * S_LEN + s]
                        = f2b(val);
                }
            }
    }
}

// Output GEMM staged: A bf16 [4096][1024], W bf16 [1024][1024], C fp32. grid (32, 8).
__global__ __launch_bounds__(256) void gemm_out_s(
    const u16* __restrict__ A, const u16* __restrict__ W,
    const float* __restrict__ bias, float* __restrict__ C)
{
    __shared__ u16 lA[128 * 32];
    __shared__ u16 lB[128 * 32];
    const int tid = threadIdx.x;
    const int lane = tid & 63, wave = tid >> 6;
    const int r15 = lane & 15, g = lane >> 4;
    const int m0 = blockIdx.x * 128;
    const int n0 = blockIdx.y * 128;

    const int srow = tid >> 2, scol = (tid & 3) * 8;
    const u16* aSrc = A + (size_t)(m0 + srow) * DMODEL + scol;
    const u16* wSrc = W + (size_t)(n0 + srow) * DMODEL + scol;
    const int ldsW = wave * 1024;
    const int mrow = (wave >> 1) * 64, nrow = (wave & 1) * 64;

    f32x4 acc[4][4] = {};
    for (int kk = 0; kk < DMODEL; kk += 32) {
        __syncthreads();
        #pragma unroll
        for (int ro = 0; ro < 2; ro++) {
            __builtin_amdgcn_global_load_lds(
                (gvoid*)(aSrc + (size_t)ro * 64 * DMODEL + kk),
                (lvoid*)((char*)lA + ro * 4096 + ldsW), 16, 0, 0);
            __builtin_amdgcn_global_load_lds(
                (gvoid*)(wSrc + (size_t)ro * 64 * DMODEL + kk),
                (lvoid*)((char*)lB + ro * 4096 + ldsW), 16, 0, 0);
        }
        __syncthreads();
        bf16x8 af[4], bf[4];
        #pragma unroll
        for (int mi = 0; mi < 4; mi++)
            af[mi] = *reinterpret_cast<const bf16x8*>(&lA[(mrow + mi * 16 + r15) * 32 + g * 8]);
        #pragma unroll
        for (int ni = 0; ni < 4; ni++)
            bf[ni] = *reinterpret_cast<const bf16x8*>(&lB[(nrow + ni * 16 + r15) * 32 + g * 8]);
        #pragma unroll
        for (int mi = 0; mi < 4; mi++)
            #pragma unroll
            for (int ni = 0; ni < 4; ni++)
                acc[mi][ni] = __builtin_amdgcn_mfma_f32_16x16x32_bf16(
                    af[mi], bf[ni], acc[mi][ni], 0, 0, 0);
    }
    #pragma unroll
    for (int ni = 0; ni < 4; ni++) {
        const int col = n0 + nrow + ni * 16 + r15;
        const float bv_ = bias[col];
        #pragma unroll
        for (int mi = 0; mi < 4; mi++)
            #pragma unroll
            for (int r = 0; r < 4; r++) {
                const int row = m0 + mrow + mi * 16 + g * 4 + r;
                C[(size_t)row * DMODEL + col] = acc[mi][ni][r] + bv_;
            }
    }
}

// ---------------- fallback (fp32 direct) kernels, round-6 verbatim ----------------
template<bool ABF, bool WBF>
__global__ __launch_bounds__(256) void gemm_qkv_t(
    const void* __restrict__ A_,
    const void* __restrict__ Wq_, const void* __restrict__ Wk_, const void* __restrict__ Wv_,
    const float* __restrict__ bq, const float* __restrict__ bk, const float* __restrict__ bv,
    const float* __restrict__ beta,
    u16* __restrict__ qbuf, u16* __restrict__ kbuf, u16* __restrict__ vt)
{
    const int lane = threadIdx.x & 63;
    const int wave = threadIdx.x >> 6;
    const int r15 = lane & 15, g = lane >> 4;
    const int m0 = blockIdx.x * 128 + (wave >> 1) * 64;
    const int range = blockIdx.y >> 3;
    const int n0 = (blockIdx.y & 7) * 128 + (wave & 1) * 64;
    const void* W_ = (range == 0) ? Wq_ : (range == 1) ? Wk_ : Wv_;
    const float* bias = (range == 0) ? bq : (range == 1) ? bk : bv;
    const size_t aBase = (size_t)(m0 + r15) * DMODEL + g * 8;
    const size_t wBase = (size_t)(n0 + r15) * DMODEL + g * 8;
    f32x4 acc[4][4] = {};
    for (int k = 0; k < DMODEL; k += 32) {
        bf16x8 af[4], bf[4];
        #pragma unroll
        for (int mi = 0; mi < 4; mi++) af[mi] = ldrow<ABF>(A_, aBase + (size_t)mi * 16 * DMODEL + k);
        #pragma unroll
        for (int ni = 0; ni < 4; ni++) bf[ni] = ldrow<WBF>(W_, wBase + (size_t)ni * 16 * DMODEL + k);
        #pragma unroll
        for (int mi = 0; mi < 4; mi++)
            #pragma unroll
            for (int ni = 0; ni < 4; ni++)
                acc[mi][ni] = __builtin_amdgcn_mfma_f32_16x16x32_bf16(
                    af[mi], bf[ni], acc[mi][ni], 0, 0, 0);
    }
    #pragma unroll
    for (int ni = 0; ni < 4; ni++) {
        const int col = n0 + ni * 16 + r15;
        const float bv_ = bias[col];
        float scale = 1.0f;
        if (range == 0) scale = 1.0f / (8.0f * __expf(beta[col >> 6]));
        #pragma unroll
        for (int mi = 0; mi < 4; mi++)
            #pragma unroll
            for (int r = 0; r < 4; r++) {
                const int row = m0 + mi * 16 + g * 4 + r;
                const float val = acc[mi][ni][r] + bv_;
                if (range == 0) {
                    qbuf[(size_t)row * DMODEL + col] = f2b(val * scale);
                } else if (range == 1) {
                    kbuf[(size_t)row * DMODEL + col] = f2b(val);
                } else {
                    const int b = row & 1, s = row >> 1;
                    vt[((size_t)(b * NHEAD + (col >> 6)) * DHEAD + (col & 63)) * S_LEN + s]
                        = f2b(val);
                }
            }
    }
}

template<bool WBF>
__global__ __launch_bounds__(256) void gemm_out_t(
    const u16* __restrict__ A, const void* __restrict__ W_,
    const float* __restrict__ bias, float* __restrict__ C)
{
    const int lane = threadIdx.x & 63;
    const int wave = threadIdx.x >> 6;
    const int r15 = lane & 15, g = lane >> 4;
    const int m0 = blockIdx.x * 64 + (wave >> 1) * 32;
    const int n0 = blockIdx.y * 128 + (wave & 1) * 64;
    const u16* a0 = A + (size_t)(m0 + r15) * DMODEL + g * 8;
    const size_t wBase = (size_t)(n0 + r15) * DMODEL + g * 8;
    f32x4 acc[2][4] = {};
    for (int k = 0; k < DMODEL; k += 32) {
        bf16x8 af[2], bf[4];
        #pragma unroll
        for (int mi = 0; mi < 2; mi++)
            af[mi] = *reinterpret_cast<const bf16x8*>(a0 + (size_t)mi * 16 * DMODEL + k);
        #pragma unroll
        for (int ni = 0; ni < 4; ni++) bf[ni] = ldrow<WBF>(W_, wBase + (size_t)ni * 16 * DMODEL + k);
        #pragma unroll
        for (int mi = 0; mi < 2; mi++)
            #pragma unroll
            for (int ni = 0; ni < 4; ni++)
                acc[mi][ni] = __builtin_amdgcn_mfma_f32_16x16x32_bf16(
                    af[mi], bf[ni], acc[mi][ni], 0, 0, 0);
    }
    #pragma unroll
    for (int ni = 0; ni < 4; ni++) {
        const int col = n0 + ni * 16 + r15;
        const float bv_ = bias[col];
        #pragma unroll
        for (int mi = 0; mi < 2; mi++)
            #pragma unroll
            for (int r = 0; r < 4; r++) {
                const int row = m0 + mi * 16 + g * 4 + r;
                C[(size_t)row * DMODEL + col] = acc[mi][ni][r] + bv_;
            }
    }
}

// Sliding-window attention, Q pre-projected/pre-scaled, V transposed. (unchanged)
__global__ __launch_bounds__(256) void attn2(
    const u16* __restrict__ qb, const u16* __restrict__ kb,
    const u16* __restrict__ vt, u16* __restrict__ O)
{
    const int lane = threadIdx.x & 63;
    const int wave = threadIdx.x >> 6;
    const int wid = blockIdx.x * 4 + wave;
    const int qt = wid & (S_LEN / 16 - 1);
    const int h  = (wid >> 7) & (NHEAD - 1);
    const int b  = wid >> 11;
    const int qstart = qt * 16;
    const int r15 = lane & 15, g = lane >> 4;
    const int i_glob = qstart + r15;

    const u16* qrow = qb + ((size_t)i_glob * BATCH + b) * DMODEL + h * DHEAD;
    const bf16x8 qf0 = *reinterpret_cast<const bf16x8*>(qrow + g * 8);
    const bf16x8 qf1 = *reinterpret_cast<const bf16x8*>(qrow + 32 + g * 8);
    const u16* vbase = vt + (size_t)(b * NHEAD + h) * DHEAD * S_LEN;

    float m = -1e30f, lsum = 0.0f;
    f32x4 o[4] = {};
    const int kt0 = (qstart >= WINDOW) ? (qstart - WINDOW) : 0;

    for (int kt = kt0; kt <= qstart; kt += 32) {
        f32x4 st0 = {0.f, 0.f, 0.f, 0.f}, st1 = {0.f, 0.f, 0.f, 0.f};
        {
            const int kr = min(kt + r15, S_LEN - 1);
            const u16* kp = kb + ((size_t)kr * BATCH + b) * DMODEL + h * DHEAD;
            const bf16x8 ka  = *reinterpret_cast<const bf16x8*>(kp + g * 8);
            const bf16x8 kb2 = *reinterpret_cast<const bf16x8*>(kp + 32 + g * 8);
            st0 = __builtin_amdgcn_mfma_f32_16x16x32_bf16(ka,  qf0, st0, 0, 0, 0);
            st0 = __builtin_amdgcn_mfma_f32_16x16x32_bf16(kb2, qf1, st0, 0, 0, 0);
        }
        {
            const int kr = min(kt + 16 + r15, S_LEN - 1);
            const u16* kp = kb + ((size_t)kr * BATCH + b) * DMODEL + h * DHEAD;
            const bf16x8 ka  = *reinterpret_cast<const bf16x8*>(kp + g * 8);
            const bf16x8 kb2 = *reinterpret_cast<const bf16x8*>(kp + 32 + g * 8);
            st1 = __builtin_amdgcn_mfma_f32_16x16x32_bf16(ka,  qf0, st1, 0, 0, 0);
            st1 = __builtin_amdgcn_mfma_f32_16x16x32_bf16(kb2, qf1, st1, 0, 0, 0);
        }

        float p0[4], p1[4];
        #pragma unroll
        for (int r = 0; r < 4; r++) {
            const int j0 = kt + g * 4 + r;
            const int d0 = i_glob - j0;
            p0[r] = (d0 < 0 || d0 >= WINDOW) ? -3e38f : st0[r];
            const int j1 = kt + 16 + g * 4 + r;
            const int d1 = i_glob - j1;
            p1[r] = (d1 < 0 || d1 >= WINDOW) ? -3e38f : st1[r];
        }
        float pmax = -3e38f;
        #pragma unroll
        for (int r = 0; r < 4; r++) pmax = fmaxf(pmax, fmaxf(p0[r], p1[r]));
        pmax = fmaxf(pmax, __shfl_xor(pmax, 16));
        pmax = fmaxf(pmax, __shfl_xor(pmax, 32));
        const float mnew = fmaxf(m, pmax);
        const float alpha = __expf(m - mnew);
        float psum = 0.0f;
        #pragma unroll
        for (int r = 0; r < 4; r++) {
            p0[r] = __expf(p0[r] - mnew);
            p1[r] = __expf(p1[r] - mnew);
            psum += p0[r] + p1[r];
        }
        psum += __shfl_xor(psum, 16);
        psum += __shfl_xor(psum, 32);
        lsum = lsum * alpha + psum;
        m = mnew;
        #pragma unroll
        for (int c = 0; c < 4; c++)
            #pragma unroll
            for (int r = 0; r < 4; r++) o[c][r] *= alpha;

        bf16x8 pf;
        const int base = ((g & 1) * 2) * 16 + r15;
        #pragma unroll
        for (int i = 0; i < 8; i++) {
            const int src = base + (i >> 2) * 16;
            const float v0 = __shfl(p0[i & 3], src);
            const float v1 = __shfl(p1[i & 3], src);
            pf[i] = (short)f2b((g < 2) ? v0 : v1);
        }

        int srow = kt + g * 8;
        if (srow >= S_LEN) srow = 0;
        #pragma unroll
        for (int c = 0; c < 4; c++) {
            const bf16x8 vf = *reinterpret_cast<const bf16x8*>(
                vbase + (size_t)(c * 16 + r15) * S_LEN + srow);
            o[c] = __builtin_amdgcn_mfma_f32_16x16x32_bf16(vf, pf, o[c], 0, 0, 0);
        }
    }

    const float inv = 1.0f / lsum;
    #pragma unroll
    for (int c = 0; c < 4; c++)
        #pragma unroll
        for (int r = 0; r < 4; r++) {
            const int dh = c * 16 + g * 4 + r;
            O[((size_t)i_glob * BATCH + b) * DMODEL + h * DHEAD + dh] = f2b(o[c][r] * inv);
        }
}

extern "C" void kernel_launch(void* const* d_in, const int* in_sizes, int n_in,
                              void* d_out, int out_size, void* d_ws, size_t ws_size,
                              hipStream_t stream) {
    const float* x    = (const float*)d_in[0];
    const float* Wq   = (const float*)d_in[1];
    const float* bq   = (const float*)d_in[2];
    const float* Wk   = (const float*)d_in[3];
    const float* bk   = (const float*)d_in[4];
    const float* Wv   = (const float*)d_in[5];
    const float* bv   = (const float*)d_in[6];
    const float* Wo   = (const float*)d_in[7];
    const float* bo   = (const float*)d_in[8];
    const float* beta = (const float*)d_in[9];
    float* out = (float*)d_out;
    u16* ws = (u16*)d_ws;

    const size_t M4 = (size_t)MROWS * DMODEL;   // 4M elems
    u16* qbuf = (u16*)d_out;        // d_out[0:8MB]  (overwritten by final GEMM)
    u16* kbuf = (u16*)d_out + M4;   // d_out[8:16MB]
    u16* vtb  = ws;                 // 8 MB  V^T [b][h][dh][s]
    u16* abuf = ws + M4;            // 8 MB  attention out

    const int nattn = BATCH * NHEAD * (S_LEN / 16) / 4;  // 1024 blocks
    dim3 gqkv(MROWS / 128, 24);     // 768 blocks
    dim3 gout(MROWS / 128, 8);      // 256 blocks

    if (ws_size >= (size_t)32 * 1024 * 1024) {
        u16* xb  = ws + 2 * M4;             // 8 MB
        u16* wb  = ws + 3 * M4;             // 6 MB  [Wq;Wk;Wv] bf16
        u16* wob = ws + 3 * M4 + 3145728;   // 2 MB
        cast_all<<<4096, 256, 0, stream>>>(x, Wq, Wk, Wv, Wo, xb, wb, wob);
        gemm_qkv_s<<<gqkv, 256, 0, stream>>>(xb, wb, bq, bk, bv, beta, qbuf, kbuf, vtb);
        attn2<<<nattn, 256, 0, stream>>>(qbuf, kbuf, vtb, abuf);
        gemm_out_s<<<gout, 256, 0, stream>>>(abuf, wob, bo, out);
    } else {
        dim3 gout2(MROWS / 64, 8);
        gemm_qkv_t<false, false><<<gqkv, 256, 0, stream>>>(
            x, Wq, Wk, Wv, bq, bk, bv, beta, qbuf, kbuf, vtb);
        attn2<<<nattn, 256, 0, stream>>>(qbuf, kbuf, vtb, abuf);
        gemm_out_t<false><<<gout2, 256, 0, stream>>>(abuf, Wo, bo, out);
    }
}